// Round 6
// baseline (567.588 us; speedup 1.0000x reference)
//
#include <hip/hip_runtime.h>
#include <stdint.h>

// Contrast loss, fully fused on-GPU:
//  0) prep: pack pos -> bits P[N][N/32]; cast z/W to bf16   (one launch)
//  1) h  = ELU(z @ W1^T + b1)          (bf16 MFMA GEMM, bf16 out)
//  2) zp = h @ W2^T + b2               (bf16 MFMA GEMM, f32 out)
//  3) zn = zp / |zp| (mp side * 1/tau), fp8 e4m3, stored in MFMA-fragment
//     layout znL[r>>4][k>>5][r&15][32B] -> sim frag loads are contiguous 2KB
//  4) sim: S = zn_mp @ zn_sc^T via MX-fp8 MFMA, NO LDS staging, NO K-loop
//     barriers (frags loaded straight from global, L2/L3-resident);
//     e = exp(S); masked row/col partials -> unique slots (no atomics)
//  5) two-stage reduction -> scalar loss

#define NN 8192
#define HH 512
#define TAUF 0.8f
#define EPSF 1e-8f
#define NW (NN / 32)

typedef __attribute__((ext_vector_type(8))) short short8;
typedef __attribute__((ext_vector_type(4))) float f32x4;
typedef __attribute__((ext_vector_type(4))) int i32x4;
typedef __attribute__((ext_vector_type(8))) int i32x8;
typedef __attribute__((ext_vector_type(4))) unsigned short u16x4;
typedef unsigned short u16;
typedef unsigned int u32;
typedef uint8_t u8;

typedef __attribute__((address_space(1))) void GV;
typedef __attribute__((address_space(3))) void LV;

__device__ __forceinline__ void g2l16(const void* g, void* l) {
  __builtin_amdgcn_global_load_lds((const GV*)g, (LV*)l, 16, 0, 0);
}

__device__ __forceinline__ u16 f2bf(float x) {  // RNE f32->bf16
  u32 u = __builtin_bit_cast(u32, x);
  u = (u + 0x7fffu + ((u >> 16) & 1u)) >> 16;
  return (u16)u;
}

// software f32 -> fp8 e4m3fn (OCP), RNE. |x| < 1 in our use.
__device__ __forceinline__ u32 f2fp8(float x) {
  u32 u = __builtin_bit_cast(u32, x);
  u32 s = (u >> 31) << 7;
  float a = fabsf(x);
  if (a >= 0.015625f) {
    u32 b = __builtin_bit_cast(u32, a);
    b += 0x7FFFFu + ((b >> 20) & 1u);
    u32 e = (b >> 23) - 127u + 7u;
    u32 m = (b >> 20) & 7u;
    return s | (e << 3) | m;
  } else {
    int m = (int)rintf(a * 512.0f);
    return s | (u32)m;
  }
}

__device__ __forceinline__ void cast8(const float* __restrict__ in, u16* __restrict__ out, int i) {
  f32x4 a = *(const f32x4*)(in + i);
  f32x4 b = *(const f32x4*)(in + i + 4);
  u16 o[8];
  o[0] = f2bf(a.x); o[1] = f2bf(a.y); o[2] = f2bf(a.z); o[3] = f2bf(a.w);
  o[4] = f2bf(b.x); o[5] = f2bf(b.y); o[6] = f2bf(b.z); o[7] = f2bf(b.w);
  i32x4 v;
  v.x = (int)(o[0] | ((u32)o[1] << 16)); v.y = (int)(o[2] | ((u32)o[3] << 16));
  v.z = (int)(o[4] | ((u32)o[5] << 16)); v.w = (int)(o[6] | ((u32)o[7] << 16));
  *(i32x4*)(out + i) = v;
}

// ---------------- merged prep: pack pos + all bf16 casts ----------------
__global__ __launch_bounds__(256)
void prep_kernel(const int* __restrict__ pos, u32* __restrict__ P,
                 const float* __restrict__ z_mp, u16* __restrict__ zbA,
                 const float* __restrict__ z_sc, u16* __restrict__ zbB,
                 const float* __restrict__ W1, u16* __restrict__ W1b,
                 const float* __restrict__ W2, u16* __restrict__ W2b) {
  int b = blockIdx.x, tid = threadIdx.x;
  if (b < 8192) {
    int gid = b * 256 + tid;
    const int* src = pos + (size_t)gid * 32;
    u32 w = 0;
#pragma unroll
    for (int c = 0; c < 8; ++c) {
      i32x4 p = *(const i32x4*)(src + c * 4);
      w |= ((u32)p.x & 1u) << (c * 4);
      w |= ((u32)p.y & 1u) << (c * 4 + 1);
      w |= ((u32)p.z & 1u) << (c * 4 + 2);
      w |= ((u32)p.w & 1u) << (c * 4 + 3);
    }
    P[gid] = w;
  } else if (b < 10240) {
    cast8(z_mp, zbA, ((b - 8192) * 256 + tid) * 8);
  } else if (b < 12288) {
    cast8(z_sc, zbB, ((b - 10240) * 256 + tid) * 8);
  } else if (b < 12416) {
    cast8(W1, W1b, ((b - 12288) * 256 + tid) * 8);
  } else {
    cast8(W2, W2b, ((b - 12416) * 256 + tid) * 8);
  }
}

// ---------------- projection GEMM: C = A @ W^T (+bias), tile 128x128, BK=32 ----------------
template <int EPI>
__global__ __launch_bounds__(256)
void gemm_proj(const u16* __restrict__ A1, const u16* __restrict__ A2,
               const u16* __restrict__ W, const float* __restrict__ bias,
               void* __restrict__ out1, void* __restrict__ out2) {
  __shared__ __align__(16) u16 As[128 * 32];
  __shared__ __align__(16) u16 Bs[128 * 32];
  const int tid = threadIdx.x;
  const int lane = tid & 63, w = tid >> 6;
  const int lo = lane & 15, quad = lane >> 4;
  const int wy = w >> 1, wx = w & 1;
  const u16* A; char* Out; int m0;
  if (blockIdx.y < 64) { A = A1; Out = (char*)out1; m0 = blockIdx.y * 128; }
  else                 { A = A2; Out = (char*)out2; m0 = (blockIdx.y - 64) * 128; }
  const int n0 = blockIdx.x * 128;
  const int srow = w * 16 + (lane >> 2);
  const int skel = (lane & 3) * 8;
  char* AsB = (char*)As; char* BsB = (char*)Bs;
  f32x4 acc[4][4] = {};

  for (int k0 = 0; k0 < HH; k0 += 32) {
    const u16* ga = A + (size_t)(m0 + srow) * HH + k0 + skel;
    const u16* gb = W + (size_t)(n0 + srow) * HH + k0 + skel;
    g2l16(ga, AsB + w * 1024);
    g2l16(ga + (size_t)64 * HH, AsB + w * 1024 + 4096);
    g2l16(gb, BsB + w * 1024);
    g2l16(gb + (size_t)64 * HH, BsB + w * 1024 + 4096);
    asm volatile("s_waitcnt vmcnt(0)" ::: "memory");
    __syncthreads();
    short8 aF[4], bF[4];
#pragma unroll
    for (int mi = 0; mi < 4; ++mi)
      aF[mi] = *(const short8*)(AsB + (wy * 64 + mi * 16 + lo) * 64 + quad * 16);
#pragma unroll
    for (int ni = 0; ni < 4; ++ni)
      bF[ni] = *(const short8*)(BsB + (wx * 64 + ni * 16 + lo) * 64 + quad * 16);
#pragma unroll
    for (int mi = 0; mi < 4; ++mi)
#pragma unroll
      for (int ni = 0; ni < 4; ++ni)
        acc[mi][ni] = __builtin_amdgcn_mfma_f32_16x16x32_bf16(aF[mi], bF[ni], acc[mi][ni], 0, 0, 0);
    __syncthreads();
  }
#pragma unroll
  for (int mi = 0; mi < 4; ++mi) {
    int rl = wy * 64 + mi * 16 + quad * 4;
#pragma unroll
    for (int ni = 0; ni < 4; ++ni) {
      int cl = wx * 64 + ni * 16 + lo;
      float bv = bias[n0 + cl];
#pragma unroll
      for (int r = 0; r < 4; ++r) {
        float v = acc[mi][ni][r] + bv;
        size_t idx = (size_t)(m0 + rl + r) * HH + (n0 + cl);
        if (EPI == 0) {
          if (v < 0.f) v = __expf(v) - 1.f;   // ELU
          ((u16*)Out)[idx] = f2bf(v);
        } else {
          ((float*)Out)[idx] = v;
        }
      }
    }
  }
}

// ---------------- row-normalize -> fp8, write MFMA-fragment layout ----------------
// znL flat addr for (row r, byte k): (r>>4)*8192 + (k>>5)*512 + (r&15)*32 + (k&31)
__global__ void norm_kernel(const float* __restrict__ zpA, u8* __restrict__ znA,
                            const float* __restrict__ zpB, u8* __restrict__ znB) {
  const int row = blockIdx.x & (NN - 1);
  const bool isA = blockIdx.x < NN;
  const float* src = (isA ? zpA : zpB) + (size_t)row * HH;
  u8* dst = (isA ? znA : znB);
  const float scale = isA ? (1.0f / TAUF) : 1.0f;
  const int t = threadIdx.x;  // 128
  f32x4 v = *(const f32x4*)(src + t * 4);
  float ss = v.x * v.x + v.y * v.y + v.z * v.z + v.w * v.w;
#pragma unroll
  for (int d = 1; d < 64; d <<= 1) ss += __shfl_xor(ss, d, 64);
  __shared__ float red[2];
  if ((t & 63) == 0) red[t >> 6] = ss;
  __syncthreads();
  float inv = scale * rsqrtf(red[0] + red[1]);
  u32 o = f2fp8(v.x * inv) | (f2fp8(v.y * inv) << 8) |
          (f2fp8(v.z * inv) << 16) | (f2fp8(v.w * inv) << 24);
  // k = t*4 -> chunk c = t>>3, byte-in-chunk = (t&7)*4
  *(u32*)(dst + (size_t)(row >> 4) * 8192 + (t >> 3) * 512 + (row & 15) * 32 + (t & 7) * 4) = o;
}

__device__ __forceinline__ i32x8 ld_frag(const u8* p) {
  i32x4 p0 = *(const i32x4*)p;
  i32x4 p1 = *(const i32x4*)(p + 16);
  return __builtin_shufflevector(p0, p1, 0, 1, 2, 3, 4, 5, 6, 7);
}

// ---------------- similarity GEMM (MX-fp8, no LDS staging) + reductions ----------------
__global__ __launch_bounds__(256)
void sim_kernel(const u8* __restrict__ Az, const u8* __restrict__ Bz,
                const u32* __restrict__ Pbits,
                float* __restrict__ rowpart, float* __restrict__ posrowpart,
                float* __restrict__ colpart, float* __restrict__ poscolpart) {
  __shared__ u32 PBi[128 * 4];
  __shared__ u32 PBj[128 * 4];
  const int tid = threadIdx.x;
  const int lane = tid & 63, w = tid >> 6;
  const int lo = lane & 15, quad = lane >> 4;
  const int wy = w >> 1, wx = w & 1;

  const int bid = blockIdx.x + (int)gridDim.x * blockIdx.y;
  const int xcd = bid & 7, s = bid >> 3;
  const int by = xcd * 8 + (s >> 6);
  const int bx = s & 63;
  const int i0 = by * 128, j0 = bx * 128;

  // prefetch pos bits into registers; they land during the GEMM
  const int il = tid >> 1, w2 = (tid & 1) * 2;
  const u32* PiSrc = Pbits + (size_t)(i0 + il) * NW + (j0 >> 5) + w2;
  const u32* PjSrc = Pbits + (size_t)(j0 + il) * NW + (i0 >> 5) + w2;
  u32 pa0 = PiSrc[0], pa1 = PiSrc[1], pb0 = PjSrc[0], pb1 = PjSrc[1];

  // fragment base pointers: row-group rg = (panel>>4) + wv*4 + t, chunk = kq*4+quad
  const int lof = quad * 512 + lo * 32;
  const u8* Ab = Az + (size_t)((i0 >> 4) + wy * 4) * 8192 + lof;
  const u8* Bb = Bz + (size_t)((j0 >> 4) + wx * 4) * 8192 + lof;

  f32x4 acc[4][4] = {};
  i32x8 aC[4], bC[4], aN[4], bN[4];
#pragma unroll
  for (int t = 0; t < 4; ++t) {
    aC[t] = ld_frag(Ab + (size_t)t * 8192);
    bC[t] = ld_frag(Bb + (size_t)t * 8192);
  }
#pragma unroll
  for (int kq = 0; kq < 4; ++kq) {
    if (kq < 3) {
#pragma unroll
      for (int t = 0; t < 4; ++t) {
        aN[t] = ld_frag(Ab + (size_t)t * 8192 + (kq + 1) * 2048);
        bN[t] = ld_frag(Bb + (size_t)t * 8192 + (kq + 1) * 2048);
      }
    }
#pragma unroll
    for (int mi = 0; mi < 4; ++mi)
#pragma unroll
      for (int ni = 0; ni < 4; ++ni)
        acc[mi][ni] = __builtin_amdgcn_mfma_scale_f32_16x16x128_f8f6f4(
            aC[mi], bC[ni], acc[mi][ni], 0, 0, 0, 127, 0, 127);  // e8m0 127 = 1.0
    if (kq < 3) {
#pragma unroll
      for (int t = 0; t < 4; ++t) { aC[t] = aN[t]; bC[t] = bN[t]; }
    }
  }

  // store prefetched pos bits to LDS
  PBi[il * 4 + w2] = pa0; PBi[il * 4 + w2 + 1] = pa1;
  PBj[il * 4 + w2] = pb0; PBj[il * 4 + w2 + 1] = pb1;

  // e = exp(cos/tau)
#pragma unroll
  for (int mi = 0; mi < 4; ++mi)
#pragma unroll
    for (int ni = 0; ni < 4; ++ni)
#pragma unroll
      for (int r = 0; r < 4; ++r)
        acc[mi][ni][r] = __expf(acc[mi][ni][r]);

  __syncthreads();

  const int rowb = wy * 64 + quad * 4;
  const int colb = wx * 64 + lo;

  // row reductions -> slot (bx*2 + wx)
#pragma unroll
  for (int mi = 0; mi < 4; ++mi) {
    int rl = rowb + mi * 16;
    float rs[4], pr[4];
#pragma unroll
    for (int r = 0; r < 4; ++r) {
      u32 W0 = PBi[(rl + r) * 4 + wx * 2];
      u32 W1 = PBi[(rl + r) * 4 + wx * 2 + 1];
      float e0 = acc[mi][0][r], e1 = acc[mi][1][r];
      float e2 = acc[mi][2][r], e3 = acc[mi][3][r];
      rs[r] = (e0 + e1) + (e2 + e3);
      pr[r] = (((W0 >> lo) & 1u) ? e0 : 0.f) + (((W0 >> (16 + lo)) & 1u) ? e1 : 0.f) +
              (((W1 >> lo) & 1u) ? e2 : 0.f) + (((W1 >> (16 + lo)) & 1u) ? e3 : 0.f);
    }
#pragma unroll
    for (int d = 1; d < 16; d <<= 1) {
#pragma unroll
      for (int r = 0; r < 4; ++r) {
        rs[r] += __shfl_xor(rs[r], d, 64);
        pr[r] += __shfl_xor(pr[r], d, 64);
      }
    }
    if (lo == 0) {
      float* rp = rowpart + (size_t)(bx * 2 + wx) * NN;
      float* pp = posrowpart + (size_t)(bx * 2 + wx) * NN;
#pragma unroll
      for (int r = 0; r < 4; ++r) {
        rp[i0 + rl + r] = rs[r];
        pp[i0 + rl + r] = pr[r];
      }
    }
  }

  // col reductions -> slot (by*2 + wy)
#pragma unroll
  for (int ni = 0; ni < 4; ++ni) {
    int cl = colb + ni * 16;
    u32 W0 = PBj[cl * 4 + wy * 2];
    u32 W1 = PBj[cl * 4 + wy * 2 + 1];
    float cs = 0.f, pc = 0.f;
#pragma unroll
    for (int mi = 0; mi < 4; ++mi) {
      u32 W = (mi < 2) ? W0 : W1;
      int sh = (mi & 1) * 16 + quad * 4;
#pragma unroll
      for (int r = 0; r < 4; ++r) {
        float e = acc[mi][ni][r];
        cs += e;
        pc += ((W >> (sh + r)) & 1u) ? e : 0.f;
      }
    }
    cs += __shfl_xor(cs, 16, 64); cs += __shfl_xor(cs, 32, 64);
    pc += __shfl_xor(pc, 16, 64); pc += __shfl_xor(pc, 32, 64);
    if (quad == 0) {
      colpart[(size_t)(by * 2 + wy) * NN + j0 + cl] = cs;
      poscolpart[(size_t)(by * 2 + wy) * NN + j0 + cl] = pc;
    }
  }
}

// ---------------- stage-1 reduce ----------------
__global__ __launch_bounds__(256)
void reduce1_kernel(const float* __restrict__ rowpart, const float* __restrict__ posrowpart,
                    const float* __restrict__ colpart, const float* __restrict__ poscolpart,
                    float* __restrict__ red) {
  int t = threadIdx.x;
  int i = blockIdx.x * 128 + (t >> 1);
  int half = t & 1;
  float rs = 0.f, pr = 0.f, cs = 0.f, pc = 0.f;
  for (int s = half * 64; s < half * 64 + 64; ++s) {
    rs += rowpart[(size_t)s * NN + i];
    pr += posrowpart[(size_t)s * NN + i];
    cs += colpart[(size_t)s * NN + i];
    pc += poscolpart[(size_t)s * NN + i];
  }
  rs += __shfl_xor(rs, 1, 64); pr += __shfl_xor(pr, 1, 64);
  cs += __shfl_xor(cs, 1, 64); pc += __shfl_xor(pc, 1, 64);
  float term = (half == 0) ? (__logf(pr / (rs + EPSF)) + __logf(pc / (cs + EPSF))) : 0.f;
#pragma unroll
  for (int d = 2; d < 64; d <<= 1) term += __shfl_xor(term, d, 64);
  __shared__ float rsh[4];
  if ((t & 63) == 0) rsh[t >> 6] = term;
  __syncthreads();
  if (t == 0) red[blockIdx.x] = rsh[0] + rsh[1] + rsh[2] + rsh[3];
}

__global__ void reduce2_kernel(const float* __restrict__ red, float* __restrict__ out) {
  float s = red[threadIdx.x];  // 64 threads
#pragma unroll
  for (int d = 1; d < 64; d <<= 1) s += __shfl_xor(s, d, 64);
  if (threadIdx.x == 0) out[0] = -0.5f * s / (float)NN;
}

extern "C" void kernel_launch(void* const* d_in, const int* in_sizes, int n_in,
                              void* d_out, int out_size, void* d_ws, size_t ws_size,
                              hipStream_t stream) {
  const float* z_mp = (const float*)d_in[0];
  const float* z_sc = (const float*)d_in[1];
  const int* pos = (const int*)d_in[2];
  const float* W1 = (const float*)d_in[3];
  const float* b1 = (const float*)d_in[4];
  const float* W2 = (const float*)d_in[5];
  const float* b2 = (const float*)d_in[6];
  float* out = (float*)d_out;

  char* ws = (char*)d_ws;
  u32* Pbits = (u32*)(ws);                    // [0, 8MB)
  u16* zbA = (u16*)(ws + 8388608);            // [8, 16MB)
  u16* zbB = (u16*)(ws + 16777216);           // [16, 24MB)
  u16* W1b = (u16*)(ws + 25165824);           // [24, 24.5MB)
  u16* W2b = (u16*)(ws + 25690112);           // [24.5, 25MB)
  u16* hA  = (u16*)(ws + 26214400);           // [25, 33MB)
  u16* hB  = (u16*)(ws + 34603008);           // [33, 41MB)
  float* zpA = (float*)(ws + 42991616);       // [41, 57MB)
  float* zpB = (float*)(ws + 59768832);       // [57, 73MB)
  u8* znA = (u8*)zbA;                         // reuse (zb dead after gemm1): 4MB
  u8* znB = (u8*)zbB;
  float* rowpart    = (float*)(ws + 26214400);  // reuse hA region (dead after gemm2)
  float* posrowpart = (float*)(ws + 30408704);
  float* colpart    = (float*)(ws + 34603008);  // reuse hB region
  float* poscolpart = (float*)(ws + 38797312);
  float* red64 = (float*)(ws + 76546048);

  prep_kernel<<<12544, 256, 0, stream>>>(pos, Pbits, z_mp, zbA, z_sc, zbB, W1, W1b, W2, W2b);

  dim3 gp(4, 128);
  gemm_proj<0><<<gp, 256, 0, stream>>>(zbA, zbB, W1b, b1, hA, hB);
  gemm_proj<1><<<gp, 256, 0, stream>>>(hA, hB, W2b, b2, zpA, zpB);

  norm_kernel<<<2 * NN, 128, 0, stream>>>(zpA, znA, zpB, znB);

  dim3 gs(64, 64);
  sim_kernel<<<gs, 256, 0, stream>>>(znA, znB, Pbits, rowpart, posrowpart, colpart, poscolpart);
  reduce1_kernel<<<64, 256, 0, stream>>>(rowpart, posrowpart, colpart, poscolpart, red64);
  reduce2_kernel<<<1, 64, 0, stream>>>(red64, out);
}

// Round 7
// 525.320 us; speedup vs baseline: 1.0805x; 1.0805x over previous
//
#include <hip/hip_runtime.h>
#include <stdint.h>

// Contrast loss, fully fused on-GPU:
//  0) prep: pack pos -> bits P[N][N/32]; cast z/W to fp8 e4m3 (one launch)
//  1) h  = ELU(z @ W1^T + b1)          (MX-fp8 MFMA GEMM, fp8 out)
//  2) zp = h @ W2^T + b2               (MX-fp8 MFMA GEMM, f32 out)
//  3) zn = zp / |zp| (mp side * 1/tau), fp8 e4m3 row-major
//  4) sim: S = zn_mp @ zn_sc^T via MX-fp8 MFMA (BK=128, LDS-staged,
//     XOR-swizzled); e = exp(S); masked row/col partials -> unique slots
//  5) two-stage reduction -> scalar loss

#define NN 8192
#define HH 512
#define TAUF 0.8f
#define EPSF 1e-8f
#define NW (NN / 32)

typedef __attribute__((ext_vector_type(4))) float f32x4;
typedef __attribute__((ext_vector_type(2))) int i32x2;
typedef __attribute__((ext_vector_type(4))) int i32x4;
typedef __attribute__((ext_vector_type(8))) int i32x8;
typedef unsigned short u16;
typedef unsigned int u32;
typedef uint8_t u8;

typedef __attribute__((address_space(1))) void GV;
typedef __attribute__((address_space(3))) void LV;

__device__ __forceinline__ void g2l16(const void* g, void* l) {
  __builtin_amdgcn_global_load_lds((const GV*)g, (LV*)l, 16, 0, 0);
}

__device__ __forceinline__ u16 f2bf(float x) {  // RNE f32->bf16
  u32 u = __builtin_bit_cast(u32, x);
  u = (u + 0x7fffu + ((u >> 16) & 1u)) >> 16;
  return (u16)u;
}

// software f32 -> fp8 e4m3fn (OCP), RNE. |x| < 448 in our use.
__device__ __forceinline__ u32 f2fp8(float x) {
  u32 u = __builtin_bit_cast(u32, x);
  u32 s = (u >> 31) << 7;
  float a = fabsf(x);
  if (a >= 0.015625f) {
    u32 b = __builtin_bit_cast(u32, a);
    b += 0x7FFFFu + ((b >> 20) & 1u);
    u32 e = (b >> 23) - 127u + 7u;
    u32 m = (b >> 20) & 7u;
    return s | (e << 3) | m;
  } else {
    int m = (int)rintf(a * 512.0f);
    return s | (u32)m;
  }
}

__device__ __forceinline__ void cast8f8(const float* __restrict__ in, u8* __restrict__ out, int i) {
  f32x4 a = *(const f32x4*)(in + i);
  f32x4 b = *(const f32x4*)(in + i + 4);
  i32x2 v;
  v.x = (int)(f2fp8(a.x) | (f2fp8(a.y) << 8) | (f2fp8(a.z) << 16) | (f2fp8(a.w) << 24));
  v.y = (int)(f2fp8(b.x) | (f2fp8(b.y) << 8) | (f2fp8(b.z) << 16) | (f2fp8(b.w) << 24));
  *(i32x2*)(out + i) = v;
}

// ---------------- merged prep: pack pos + all fp8 casts ----------------
__global__ __launch_bounds__(256)
void prep_kernel(const int* __restrict__ pos, u32* __restrict__ P,
                 const float* __restrict__ z_mp, u8* __restrict__ zbA,
                 const float* __restrict__ z_sc, u8* __restrict__ zbB,
                 const float* __restrict__ W1, u8* __restrict__ W1b,
                 const float* __restrict__ W2, u8* __restrict__ W2b) {
  int b = blockIdx.x, tid = threadIdx.x;
  if (b < 8192) {
    int gid = b * 256 + tid;
    const int* src = pos + (size_t)gid * 32;
    u32 w = 0;
#pragma unroll
    for (int c = 0; c < 8; ++c) {
      i32x4 p = *(const i32x4*)(src + c * 4);
      w |= ((u32)p.x & 1u) << (c * 4);
      w |= ((u32)p.y & 1u) << (c * 4 + 1);
      w |= ((u32)p.z & 1u) << (c * 4 + 2);
      w |= ((u32)p.w & 1u) << (c * 4 + 3);
    }
    P[gid] = w;
  } else if (b < 10240) {
    cast8f8(z_mp, zbA, ((b - 8192) * 256 + tid) * 8);
  } else if (b < 12288) {
    cast8f8(z_sc, zbB, ((b - 10240) * 256 + tid) * 8);
  } else if (b < 12416) {
    cast8f8(W1, W1b, ((b - 12288) * 256 + tid) * 8);
  } else {
    cast8f8(W2, W2b, ((b - 12416) * 256 + tid) * 8);
  }
}

// ---------------- projection GEMM: C = A @ W^T (+bias), MX-fp8, tile 128x128, BK=128 ----------------
// EPI 0: ELU -> fp8 out ; EPI 1: bias -> f32 out
template <int EPI>
__global__ __launch_bounds__(256)
void gemm_proj(const u8* __restrict__ A1, const u8* __restrict__ A2,
               const u8* __restrict__ W, const float* __restrict__ bias,
               void* __restrict__ out1, void* __restrict__ out2) {
  __shared__ __align__(16) u8 As[128 * 128];
  __shared__ __align__(16) u8 Bs[128 * 128];
  const int tid = threadIdx.x;
  const int lane = tid & 63, w = tid >> 6;
  const int lo = lane & 15, quad = lane >> 4;
  const int wy = w >> 1, wx = w & 1;
  const u8* A; char* Out; int m0;
  if (blockIdx.y < 64) { A = A1; Out = (char*)out1; m0 = blockIdx.y * 128; }
  else                 { A = A2; Out = (char*)out2; m0 = (blockIdx.y - 64) * 128; }
  const int n0 = blockIdx.x * 128;
  const int srow = lane >> 3;                   // 0..7
  const int schunk = ((lane & 7) ^ srow) * 16;  // XOR-swizzled source chunk
  char* AsB = (char*)As; char* BsB = (char*)Bs;
  f32x4 acc[4][4] = {};

  for (int k0 = 0; k0 < HH; k0 += 128) {
    const u8* ga = A + (size_t)(m0 + w * 32 + srow) * HH + k0 + schunk;
    const u8* gb = W + (size_t)(n0 + w * 32 + srow) * HH + k0 + schunk;
#pragma unroll
    for (int t = 0; t < 4; ++t) {
      g2l16(ga + (size_t)(t * 8) * HH, AsB + w * 4096 + t * 1024);
      g2l16(gb + (size_t)(t * 8) * HH, BsB + w * 4096 + t * 1024);
    }
    asm volatile("s_waitcnt vmcnt(0)" ::: "memory");
    __syncthreads();
    i32x8 aF[4], bF[4];
#pragma unroll
    for (int mi = 0; mi < 4; ++mi) {
      int ar = wy * 64 + mi * 16 + lo;
      int sw = ar & 7;
      i32x4 p0 = *(const i32x4*)(AsB + ar * 128 + ((2 * quad) ^ sw) * 16);
      i32x4 p1 = *(const i32x4*)(AsB + ar * 128 + ((2 * quad + 1) ^ sw) * 16);
      aF[mi] = __builtin_shufflevector(p0, p1, 0, 1, 2, 3, 4, 5, 6, 7);
    }
#pragma unroll
    for (int ni = 0; ni < 4; ++ni) {
      int br = wx * 64 + ni * 16 + lo;
      int sw = br & 7;
      i32x4 p0 = *(const i32x4*)(BsB + br * 128 + ((2 * quad) ^ sw) * 16);
      i32x4 p1 = *(const i32x4*)(BsB + br * 128 + ((2 * quad + 1) ^ sw) * 16);
      bF[ni] = __builtin_shufflevector(p0, p1, 0, 1, 2, 3, 4, 5, 6, 7);
    }
#pragma unroll
    for (int mi = 0; mi < 4; ++mi)
#pragma unroll
      for (int ni = 0; ni < 4; ++ni)
        acc[mi][ni] = __builtin_amdgcn_mfma_scale_f32_16x16x128_f8f6f4(
            aF[mi], bF[ni], acc[mi][ni], 0, 0, 0, 127, 0, 127);  // e8m0 127 = 1.0
    __syncthreads();
  }
#pragma unroll
  for (int mi = 0; mi < 4; ++mi) {
    int rl = wy * 64 + mi * 16 + quad * 4;
#pragma unroll
    for (int ni = 0; ni < 4; ++ni) {
      int cl = wx * 64 + ni * 16 + lo;
      float bv = bias[n0 + cl];
#pragma unroll
      for (int r = 0; r < 4; ++r) {
        float v = acc[mi][ni][r] + bv;
        size_t idx = (size_t)(m0 + rl + r) * HH + (n0 + cl);
        if (EPI == 0) {
          if (v < 0.f) v = __expf(v) - 1.f;   // ELU
          ((u8*)Out)[idx] = (u8)f2fp8(v);
        } else {
          ((float*)Out)[idx] = v;
        }
      }
    }
  }
}

// ---------------- row-normalize both zp arrays to fp8 e4m3 (one launch) ----------------
__global__ void norm_kernel(const float* __restrict__ zpA, u8* __restrict__ znA,
                            const float* __restrict__ zpB, u8* __restrict__ znB) {
  const int row = blockIdx.x & (NN - 1);
  const bool isA = blockIdx.x < NN;
  const float* src = (isA ? zpA : zpB) + (size_t)row * HH;
  u8* dst = (isA ? znA : znB) + (size_t)row * HH;
  const float scale = isA ? (1.0f / TAUF) : 1.0f;
  const int t = threadIdx.x;  // 128
  f32x4 v = *(const f32x4*)(src + t * 4);
  float ss = v.x * v.x + v.y * v.y + v.z * v.z + v.w * v.w;
#pragma unroll
  for (int d = 1; d < 64; d <<= 1) ss += __shfl_xor(ss, d, 64);
  __shared__ float red[2];
  if ((t & 63) == 0) red[t >> 6] = ss;
  __syncthreads();
  float inv = scale * rsqrtf(red[0] + red[1]);
  u32 o = f2fp8(v.x * inv) | (f2fp8(v.y * inv) << 8) |
          (f2fp8(v.z * inv) << 16) | (f2fp8(v.w * inv) << 24);
  *(u32*)(dst + t * 4) = o;
}

// ---------------- similarity GEMM (MX-fp8, BK=128, LDS-staged) + reductions ----------------
__global__ __launch_bounds__(256)
void sim_kernel(const u8* __restrict__ Az, const u8* __restrict__ Bz,
                const u32* __restrict__ Pbits,
                float* __restrict__ rowpart, float* __restrict__ posrowpart,
                float* __restrict__ colpart, float* __restrict__ poscolpart) {
  __shared__ __align__(16) u8 As[128 * 128];   // 16 KB
  __shared__ __align__(16) u8 Bs[128 * 128];   // 16 KB
  __shared__ u32 PBi[128 * 4];
  __shared__ u32 PBj[128 * 4];
  const int tid = threadIdx.x;
  const int lane = tid & 63, w = tid >> 6;
  const int lo = lane & 15, quad = lane >> 4;
  const int wy = w >> 1, wx = w & 1;

  const int bid = blockIdx.x + (int)gridDim.x * blockIdx.y;
  const int xcd = bid & 7, s = bid >> 3;
  const int by = xcd * 8 + (s >> 6);
  const int bx = s & 63;
  const int i0 = by * 128, j0 = bx * 128;

  // prefetch pos bits into registers; they land during the K-loop
  const int il = tid >> 1, w2 = (tid & 1) * 2;
  const u32* PiSrc = Pbits + (size_t)(i0 + il) * NW + (j0 >> 5) + w2;
  const u32* PjSrc = Pbits + (size_t)(j0 + il) * NW + (i0 >> 5) + w2;
  u32 pa0 = PiSrc[0], pa1 = PiSrc[1], pb0 = PjSrc[0], pb1 = PjSrc[1];

  const int srow = lane >> 3;                   // 0..7
  const int schunk = ((lane & 7) ^ srow) * 16;  // XOR-swizzled source chunk
  char* AsB = (char*)As; char* BsB = (char*)Bs;
  f32x4 acc[4][4] = {};

  for (int k0 = 0; k0 < HH; k0 += 128) {
    const u8* ga = Az + (size_t)(i0 + w * 32 + srow) * HH + k0 + schunk;
    const u8* gb = Bz + (size_t)(j0 + w * 32 + srow) * HH + k0 + schunk;
#pragma unroll
    for (int t = 0; t < 4; ++t) {
      g2l16(ga + (size_t)(t * 8) * HH, AsB + w * 4096 + t * 1024);
      g2l16(gb + (size_t)(t * 8) * HH, BsB + w * 4096 + t * 1024);
    }
    asm volatile("s_waitcnt vmcnt(0)" ::: "memory");
    __syncthreads();
    i32x8 aF[4], bF[4];
#pragma unroll
    for (int mi = 0; mi < 4; ++mi) {
      int ar = wy * 64 + mi * 16 + lo;
      int sw = ar & 7;
      i32x4 p0 = *(const i32x4*)(AsB + ar * 128 + ((2 * quad) ^ sw) * 16);
      i32x4 p1 = *(const i32x4*)(AsB + ar * 128 + ((2 * quad + 1) ^ sw) * 16);
      aF[mi] = __builtin_shufflevector(p0, p1, 0, 1, 2, 3, 4, 5, 6, 7);
    }
#pragma unroll
    for (int ni = 0; ni < 4; ++ni) {
      int br = wx * 64 + ni * 16 + lo;
      int sw = br & 7;
      i32x4 p0 = *(const i32x4*)(BsB + br * 128 + ((2 * quad) ^ sw) * 16);
      i32x4 p1 = *(const i32x4*)(BsB + br * 128 + ((2 * quad + 1) ^ sw) * 16);
      bF[ni] = __builtin_shufflevector(p0, p1, 0, 1, 2, 3, 4, 5, 6, 7);
    }
#pragma unroll
    for (int mi = 0; mi < 4; ++mi)
#pragma unroll
      for (int ni = 0; ni < 4; ++ni)
        acc[mi][ni] = __builtin_amdgcn_mfma_scale_f32_16x16x128_f8f6f4(
            aF[mi], bF[ni], acc[mi][ni], 0, 0, 0, 127, 0, 127);  // e8m0 127 = 1.0
    __syncthreads();
  }

  // store prefetched pos bits to LDS
  PBi[il * 4 + w2] = pa0; PBi[il * 4 + w2 + 1] = pa1;
  PBj[il * 4 + w2] = pb0; PBj[il * 4 + w2 + 1] = pb1;

  // e = exp(cos/tau)
#pragma unroll
  for (int mi = 0; mi < 4; ++mi)
#pragma unroll
    for (int ni = 0; ni < 4; ++ni)
#pragma unroll
      for (int r = 0; r < 4; ++r)
        acc[mi][ni][r] = __expf(acc[mi][ni][r]);

  __syncthreads();

  const int rowb = wy * 64 + quad * 4;
  const int colb = wx * 64 + lo;

  // row reductions -> slot (bx*2 + wx)
#pragma unroll
  for (int mi = 0; mi < 4; ++mi) {
    int rl = rowb + mi * 16;
    float rs[4], pr[4];
#pragma unroll
    for (int r = 0; r < 4; ++r) {
      u32 W0 = PBi[(rl + r) * 4 + wx * 2];
      u32 W1 = PBi[(rl + r) * 4 + wx * 2 + 1];
      float e0 = acc[mi][0][r], e1 = acc[mi][1][r];
      float e2 = acc[mi][2][r], e3 = acc[mi][3][r];
      rs[r] = (e0 + e1) + (e2 + e3);
      pr[r] = (((W0 >> lo) & 1u) ? e0 : 0.f) + (((W0 >> (16 + lo)) & 1u) ? e1 : 0.f) +
              (((W1 >> lo) & 1u) ? e2 : 0.f) + (((W1 >> (16 + lo)) & 1u) ? e3 : 0.f);
    }
#pragma unroll
    for (int d = 1; d < 16; d <<= 1) {
#pragma unroll
      for (int r = 0; r < 4; ++r) {
        rs[r] += __shfl_xor(rs[r], d, 64);
        pr[r] += __shfl_xor(pr[r], d, 64);
      }
    }
    if (lo == 0) {
      float* rp = rowpart + (size_t)(bx * 2 + wx) * NN;
      float* pp = posrowpart + (size_t)(bx * 2 + wx) * NN;
#pragma unroll
      for (int r = 0; r < 4; ++r) {
        rp[i0 + rl + r] = rs[r];
        pp[i0 + rl + r] = pr[r];
      }
    }
  }

  // col reductions -> slot (by*2 + wy)
#pragma unroll
  for (int ni = 0; ni < 4; ++ni) {
    int cl = colb + ni * 16;
    u32 W0 = PBj[cl * 4 + wy * 2];
    u32 W1 = PBj[cl * 4 + wy * 2 + 1];
    float cs = 0.f, pc = 0.f;
#pragma unroll
    for (int mi = 0; mi < 4; ++mi) {
      u32 W = (mi < 2) ? W0 : W1;
      int sh = (mi & 1) * 16 + quad * 4;
#pragma unroll
      for (int r = 0; r < 4; ++r) {
        float e = acc[mi][ni][r];
        cs += e;
        pc += ((W >> (sh + r)) & 1u) ? e : 0.f;
      }
    }
    cs += __shfl_xor(cs, 16, 64); cs += __shfl_xor(cs, 32, 64);
    pc += __shfl_xor(pc, 16, 64); pc += __shfl_xor(pc, 32, 64);
    if (quad == 0) {
      colpart[(size_t)(by * 2 + wy) * NN + j0 + cl] = cs;
      poscolpart[(size_t)(by * 2 + wy) * NN + j0 + cl] = pc;
    }
  }
}

// ---------------- stage-1 reduce ----------------
__global__ __launch_bounds__(256)
void reduce1_kernel(const float* __restrict__ rowpart, const float* __restrict__ posrowpart,
                    const float* __restrict__ colpart, const float* __restrict__ poscolpart,
                    float* __restrict__ red) {
  int t = threadIdx.x;
  int i = blockIdx.x * 128 + (t >> 1);
  int half = t & 1;
  float rs = 0.f, pr = 0.f, cs = 0.f, pc = 0.f;
  for (int s = half * 64; s < half * 64 + 64; ++s) {
    rs += rowpart[(size_t)s * NN + i];
    pr += posrowpart[(size_t)s * NN + i];
    cs += colpart[(size_t)s * NN + i];
    pc += poscolpart[(size_t)s * NN + i];
  }
  rs += __shfl_xor(rs, 1, 64); pr += __shfl_xor(pr, 1, 64);
  cs += __shfl_xor(cs, 1, 64); pc += __shfl_xor(pc, 1, 64);
  float term = (half == 0) ? (__logf(pr / (rs + EPSF)) + __logf(pc / (cs + EPSF))) : 0.f;
#pragma unroll
  for (int d = 2; d < 64; d <<= 1) term += __shfl_xor(term, d, 64);
  __shared__ float rsh[4];
  if ((t & 63) == 0) rsh[t >> 6] = term;
  __syncthreads();
  if (t == 0) red[blockIdx.x] = rsh[0] + rsh[1] + rsh[2] + rsh[3];
}

__global__ void reduce2_kernel(const float* __restrict__ red, float* __restrict__ out) {
  float s = red[threadIdx.x];  // 64 threads
#pragma unroll
  for (int d = 1; d < 64; d <<= 1) s += __shfl_xor(s, d, 64);
  if (threadIdx.x == 0) out[0] = -0.5f * s / (float)NN;
}

extern "C" void kernel_launch(void* const* d_in, const int* in_sizes, int n_in,
                              void* d_out, int out_size, void* d_ws, size_t ws_size,
                              hipStream_t stream) {
  const float* z_mp = (const float*)d_in[0];
  const float* z_sc = (const float*)d_in[1];
  const int* pos = (const int*)d_in[2];
  const float* W1 = (const float*)d_in[3];
  const float* b1 = (const float*)d_in[4];
  const float* W2 = (const float*)d_in[5];
  const float* b2 = (const float*)d_in[6];
  float* out = (float*)d_out;

  char* ws = (char*)d_ws;
  u32* Pbits = (u32*)(ws);                    // [0, 8MB)
  u8* zbA = (u8*)(ws + 8388608);              // 4 MB (fp8)
  u8* zbB = (u8*)(ws + 16777216);             // 4 MB
  u8* W1b = (u8*)(ws + 25165824);             // 256 KB
  u8* W2b = (u8*)(ws + 25690112);             // 256 KB
  u8* hA  = (u8*)(ws + 26214400);             // 4 MB (fp8 h)
  u8* hB  = (u8*)(ws + 34603008);             // 4 MB
  float* zpA = (float*)(ws + 42991616);       // 16 MB
  float* zpB = (float*)(ws + 59768832);       // 16 MB
  u8* znA = zbA;                              // reuse (zb dead after gemm1)
  u8* znB = zbB;
  float* rowpart    = (float*)(ws + 26214400);  // reuse hA region (dead after gemm2)
  float* posrowpart = (float*)(ws + 30408704);
  float* colpart    = (float*)(ws + 34603008);  // reuse hB region
  float* poscolpart = (float*)(ws + 38797312);
  float* red64 = (float*)(ws + 76546048);

  prep_kernel<<<12544, 256, 0, stream>>>(pos, Pbits, z_mp, zbA, z_sc, zbB, W1, W1b, W2, W2b);

  dim3 gp(4, 128);
  gemm_proj<0><<<gp, 256, 0, stream>>>(zbA, zbB, W1b, b1, hA, hB);
  gemm_proj<1><<<gp, 256, 0, stream>>>(hA, hB, W2b, b2, zpA, zpB);

  norm_kernel<<<2 * NN, 128, 0, stream>>>(zpA, znA, zpB, znB);

  dim3 gs(64, 64);
  sim_kernel<<<gs, 256, 0, stream>>>(znA, znB, Pbits, rowpart, posrowpart, colpart, poscolpart);
  reduce1_kernel<<<64, 256, 0, stream>>>(rowpart, posrowpart, colpart, poscolpart, red64);
  reduce2_kernel<<<1, 64, 0, stream>>>(red64, out);
}